// Round 1
// baseline (1518.143 us; speedup 1.0000x reference)
//
#include <hip/hip_runtime.h>

// Head layout (u32 words at ws+0):
// 0: c0 (nonzero bytes at pos%4==0)   1: c123 (nonzero bytes at pos%4!=0)
// 2: amax_hi_msg bits  3: amax_lo_msg bits  4: amax_hi_out bits  5: amax_lo_out bits
// 6: scale_hi_msg (f32) 7: scale_lo_msg 8: scale_hi_out 9: scale_lo_out

__global__ void k_zero(unsigned* p, int n) {
  int i = blockIdx.x * blockDim.x + threadIdx.x;
  for (; i < n; i += gridDim.x * blockDim.x) p[i] = 0u;
}

// Sniff mask dtype from raw bytes (reads only N bytes, safe for u8/i32/f32).
__global__ void k_detect(const unsigned char* m, unsigned* head, int nbytes) {
  int i = blockIdx.x * blockDim.x + threadIdx.x;
  int c0 = 0, c123 = 0;
  for (; i < nbytes; i += gridDim.x * blockDim.x) {
    unsigned char b = m[i];
    if (b) { if ((i & 3) == 0) c0++; else c123++; }
  }
  for (int o = 32; o; o >>= 1) { c0 += __shfl_xor(c0, o); c123 += __shfl_xor(c123, o); }
  if ((threadIdx.x & 63) == 0) {
    if (c0)   atomicAdd(&head[0], (unsigned)c0);
    if (c123) atomicAdd(&head[1], (unsigned)c123);
  }
}

// Canonicalize mask to u8 0/1. mode: c123==0 -> int32; else c0==0 -> f32; else bytes.
__global__ void k_canon(const void* mraw, const unsigned* head, unsigned char* msk, int N) {
  unsigned c0 = head[0], c123 = head[1];
  int mode = (c123 == 0u) ? 1 : ((c0 == 0u) ? 2 : 0);
  int i = blockIdx.x * blockDim.x + threadIdx.x;
  for (; i < N; i += gridDim.x * blockDim.x) {
    unsigned char v;
    if (mode == 0)      v = (((const unsigned char*)mraw)[i] != 0);
    else if (mode == 1) v = (((const int*)mraw)[i] != 0);
    else                v = (((const float*)mraw)[i] != 0.0f);
    msk[i] = v;
  }
}

// rowmax[n] = max_f |x[n,f]|. One wave per node, lane = feature (F==64).
__global__ void k_rowmax(const float* x, float* rowmax, int N) {
  int w = (int)((blockIdx.x * blockDim.x + threadIdx.x) >> 6);
  int lane = threadIdx.x & 63;
  if (w >= N) return;
  float v = fabsf(x[(size_t)w * 64 + lane]);
  for (int o = 32; o; o >>= 1) v = fmaxf(v, __shfl_xor(v, o));
  if (lane == 0) rowmax[w] = v;
}

// amax over edges: hi where mask[src], lo where !mask[src].
__global__ void k_edge_amax(const int* src, const unsigned char* msk,
                            const float* rowmax, unsigned* head, int E) {
  int e = blockIdx.x * blockDim.x + threadIdx.x;
  float hi = 0.0f, lo = 0.0f;
  for (; e < E; e += gridDim.x * blockDim.x) {
    int s = src[e];
    float r = rowmax[s];
    if (msk[s]) hi = fmaxf(hi, r); else lo = fmaxf(lo, r);
  }
  for (int o = 32; o; o >>= 1) { hi = fmaxf(hi, __shfl_xor(hi, o)); lo = fmaxf(lo, __shfl_xor(lo, o)); }
  if ((threadIdx.x & 63) == 0) {
    atomicMax(&head[2], __float_as_uint(hi));
    atomicMax(&head[3], __float_as_uint(lo));
  }
}

// which=0: msg scales from head[2,3] -> hf[6,7]; which=1: out scales head[4,5] -> hf[8,9]
__global__ void k_scales(unsigned* head, int which) {
  if (blockIdx.x == 0 && threadIdx.x == 0) {
    float* hf = (float*)head;
    int a = 2 + which * 2;
    float ah = __uint_as_float(head[a]);
    float al = __uint_as_float(head[a + 1]);
    hf[6 + which * 2]     = __fdiv_rn(fmaxf(ah, 1e-8f), 127.0f);
    hf[6 + which * 2 + 1] = __fdiv_rn(fmaxf(al, 1e-8f), 7.0f);
  }
}

// Fake-quantize all rows: in/out may alias. scale_base: 6 (msg) or 8 (out).
__global__ void k_quant_rows(const float* in, float* out, const unsigned char* msk,
                             const unsigned* head, int scale_base, int N) {
  int w = (int)((blockIdx.x * blockDim.x + threadIdx.x) >> 6);
  int lane = threadIdx.x & 63;
  if (w >= N) return;
  const float* hf = (const float*)head;
  bool m = msk[w] != 0;
  float sc = hf[scale_base + (m ? 0 : 1)];
  float qm = m ? 127.0f : 7.0f;
  float v = in[(size_t)w * 64 + lane];
  float t = __fdiv_rn(v, sc);
  t = fminf(fmaxf(t, -qm), qm);
  t = rintf(t);
  out[(size_t)w * 64 + lane] = __fmul_rn(sc, t);
}

__global__ void k_hist(const int* dst, unsigned* cnt, int E) {
  int e = blockIdx.x * blockDim.x + threadIdx.x;
  for (; e < E; e += gridDim.x * blockDim.x) atomicAdd(&cnt[dst[e]], 1u);
}

// --- 3-kernel exclusive scan over cnt[N] -> start[N], chunk = 1024 ---
__global__ void k_scan_chunk_sum(const unsigned* cnt, unsigned* csum, int N) {
  int b = blockIdx.x, base = b * 1024;
  __shared__ unsigned sh[256];
  unsigned s = 0;
  for (int i = threadIdx.x; i < 1024; i += 256) {
    int idx = base + i;
    s += (idx < N) ? cnt[idx] : 0u;
  }
  sh[threadIdx.x] = s; __syncthreads();
  for (int off = 128; off > 0; off >>= 1) {
    if (threadIdx.x < (unsigned)off) sh[threadIdx.x] += sh[threadIdx.x + off];
    __syncthreads();
  }
  if (threadIdx.x == 0) csum[b] = sh[0];
}

__global__ void k_scan_carry(const unsigned* csum, unsigned* coff, int nchunks) {
  if (blockIdx.x == 0 && threadIdx.x == 0) {
    unsigned run = 0;
    for (int b = 0; b < nchunks; b++) { coff[b] = run; run += csum[b]; }
  }
}

__global__ void k_scan_within(const unsigned* cnt, const unsigned* coff, unsigned* start, int N) {
  int b = blockIdx.x, base = b * 1024, t = threadIdx.x;
  __shared__ unsigned sh[256];
  unsigned v[4]; unsigned s = 0;
  for (int j = 0; j < 4; j++) {
    int idx = base + t * 4 + j;
    v[j] = (idx < N) ? cnt[idx] : 0u;
    s += v[j];
  }
  sh[t] = s; __syncthreads();
  for (int off = 1; off < 256; off <<= 1) {
    unsigned a = sh[t];
    unsigned add = (t >= off) ? sh[t - off] : 0u;
    __syncthreads();
    sh[t] = a + add;
    __syncthreads();
  }
  unsigned excl = (t == 0) ? 0u : sh[t - 1];
  unsigned run = coff[b] + excl;
  for (int j = 0; j < 4; j++) {
    int idx = base + t * 4 + j;
    if (idx < N) start[idx] = run;
    run += v[j];
  }
}

// Placement: pos = postincrement of start[dst]. (start becomes end-of-bucket.)
__global__ void k_place(const int* dst, unsigned* start, unsigned* order, int E) {
  int e = blockIdx.x * blockDim.x + threadIdx.x;
  for (; e < E; e += gridDim.x * blockDim.x) {
    unsigned pos = atomicAdd(&start[dst[e]], 1u);
    order[pos] = (unsigned)e;
  }
}

// Per-node insertion sort of its edge list by edge id (stable order restoration).
__global__ void k_sort(unsigned* order, const unsigned* start, const unsigned* cnt, int N) {
  int n = blockIdx.x * blockDim.x + threadIdx.x;
  for (; n < N; n += gridDim.x * blockDim.x) {
    unsigned d = cnt[n];
    unsigned s0 = start[n] - d;
    for (unsigned i = 1; i < d; i++) {
      unsigned key = order[s0 + i];
      int j = (int)i - 1;
      while (j >= 0 && order[s0 + j] > key) { order[s0 + j + 1] = order[s0 + j]; j--; }
      order[s0 + (unsigned)(j + 1)] = key;
    }
  }
}

// One wave per node: sequential (edge-order) accumulation of quantized messages.
// Also reduces per-row |aggr| max into head[4]/head[5] (order-independent atomicMax).
__global__ void k_aggr(const float* xq, const float* x, const int* src,
                       const unsigned char* msk, const unsigned* order,
                       const unsigned* start, const unsigned* cnt,
                       unsigned* head, float* out, int N, int use_xq) {
  int w = (int)((blockIdx.x * blockDim.x + threadIdx.x) >> 6);
  int lane = threadIdx.x & 63;
  if (w >= N) return;
  unsigned d = cnt[w];
  unsigned s0 = start[w] - d;
  const float* hf = (const float*)head;
  float shi = hf[6], slo = hf[7];

  unsigned dlim = d < 64u ? d : 64u;
  int mys = 0;
  if ((unsigned)lane < dlim) {
    unsigned e = order[s0 + (unsigned)lane];
    mys = src[e];
  }
  float acc = 0.0f;
  unsigned kk = 0;
  for (; kk < dlim; ++kk) {
    int sn = __shfl(mys, (int)kk);
    float v;
    if (use_xq) {
      v = xq[(size_t)sn * 64 + lane];
    } else {
      bool m = msk[sn] != 0;
      float sc = m ? shi : slo;
      float qm = m ? 127.0f : 7.0f;
      float t = __fdiv_rn(x[(size_t)sn * 64 + lane], sc);
      t = fminf(fmaxf(t, -qm), qm);
      t = rintf(t);
      v = __fmul_rn(sc, t);
    }
    acc = __fadd_rn(acc, v);
  }
  for (; kk < d; ++kk) {
    unsigned e = order[s0 + kk];
    int sn = src[e];
    float v;
    if (use_xq) {
      v = xq[(size_t)sn * 64 + lane];
    } else {
      bool m = msk[sn] != 0;
      float sc = m ? shi : slo;
      float qm = m ? 127.0f : 7.0f;
      float t = __fdiv_rn(x[(size_t)sn * 64 + lane], sc);
      t = fminf(fmaxf(t, -qm), qm);
      t = rintf(t);
      v = __fmul_rn(sc, t);
    }
    acc = __fadd_rn(acc, v);
  }
  out[(size_t)w * 64 + lane] = acc;

  float a = fabsf(acc);
  for (int o = 32; o; o >>= 1) a = fmaxf(a, __shfl_xor(a, o));
  if (lane == 0) {
    int idx = (msk[w] != 0) ? 4 : 5;
    atomicMax(&head[idx], __float_as_uint(a));
  }
}

extern "C" void kernel_launch(void* const* d_in, const int* in_sizes, int n_in,
                              void* d_out, int out_size, void* d_ws, size_t ws_size,
                              hipStream_t stream) {
  const float* x = (const float*)d_in[0];
  const int* ei = (const int*)d_in[1];
  const void* mraw = d_in[2];
  int N = in_sizes[2];
  int E = in_sizes[1] / 2;
  const int* src = ei;
  const int* dst = ei + E;
  float* out = (float*)d_out;

  char* ws = (char*)d_ws;
  size_t o_csum = 256;
  size_t o_coff = o_csum + 4096;
  size_t o_msk = o_coff + 4096;
  size_t o_rowmax = ((o_msk + (size_t)N + 255) / 256) * 256;
  size_t o_cnt = o_rowmax + (size_t)N * 4;
  size_t o_start = o_cnt + (size_t)N * 4;
  size_t o_order = o_start + (size_t)N * 4;
  size_t o_xq = o_order + (size_t)E * 4;
  size_t need_xq = o_xq + (size_t)N * 64 * 4;
  int use_xq = (ws_size >= need_xq) ? 1 : 0;

  unsigned* head = (unsigned*)(ws);
  unsigned* csum = (unsigned*)(ws + o_csum);
  unsigned* coff = (unsigned*)(ws + o_coff);
  unsigned char* msk = (unsigned char*)(ws + o_msk);
  float* rowmax = (float*)(ws + o_rowmax);
  unsigned* cnt = (unsigned*)(ws + o_cnt);
  unsigned* start = (unsigned*)(ws + o_start);
  unsigned* order = (unsigned*)(ws + o_order);
  float* xq = (float*)(ws + o_xq);

  int nchunks = (N + 1023) / 1024;
  int rowBlocks = (N + 3) / 4;  // 4 waves (nodes) per 256-thread block

  k_zero<<<16, 256, 0, stream>>>(head, 2112);          // head + csum + coff regions
  k_zero<<<256, 256, 0, stream>>>(cnt, N);
  k_detect<<<256, 256, 0, stream>>>((const unsigned char*)mraw, head, N);
  k_canon<<<(N + 255) / 256, 256, 0, stream>>>(mraw, head, msk, N);
  k_rowmax<<<rowBlocks, 256, 0, stream>>>(x, rowmax, N);
  k_edge_amax<<<1024, 256, 0, stream>>>(src, msk, rowmax, head, E);
  k_scales<<<1, 64, 0, stream>>>(head, 0);
  if (use_xq) k_quant_rows<<<rowBlocks, 256, 0, stream>>>(x, xq, msk, head, 6, N);
  k_hist<<<1024, 256, 0, stream>>>(dst, cnt, E);
  k_scan_chunk_sum<<<nchunks, 256, 0, stream>>>(cnt, csum, N);
  k_scan_carry<<<1, 64, 0, stream>>>(csum, coff, nchunks);
  k_scan_within<<<nchunks, 256, 0, stream>>>(cnt, coff, start, N);
  k_place<<<1024, 256, 0, stream>>>(dst, start, order, E);
  k_sort<<<(N + 255) / 256, 256, 0, stream>>>(order, start, cnt, N);
  k_aggr<<<rowBlocks, 256, 0, stream>>>(xq, x, src, msk, order, start, cnt, head, out, N, use_xq);
  k_scales<<<1, 64, 0, stream>>>(head, 1);
  k_quant_rows<<<rowBlocks, 256, 0, stream>>>(out, out, msk, head, 8, N);
}

// Round 2
// 334.746 us; speedup vs baseline: 4.5352x; 4.5352x over previous
//
#include <hip/hip_runtime.h>

// ws layout (bytes):
//   0     : head[64] u32   (0:c0 1:c123 ; hf[6]=shi_msg hf[7]=slo_msg hf[8]=shi_out hf[9]=slo_out)
//   256   : slot_ehi[256] u32
//   1280  : slot_elo[256] u32
//   2304  : slot_ohi[256] u32
//   3328  : slot_olo[256] u32
//   4352  : csum[1024] u32
//   8448  : coff[1024] u32
//   12544 : msk[N] u8
//   align256: rowmax[N] f32 ; cnt[N] u32 ; start[N] u32 ; align256: opay[E] u64 ; align256: xq8[N*64] i8

__global__ void k_zero(unsigned* p, int n) {
  int i = blockIdx.x * blockDim.x + threadIdx.x;
  for (; i < n; i += gridDim.x * blockDim.x) p[i] = 0u;
}

// Sniff mask dtype from raw bytes (reads only N bytes, safe for u8/i32/f32).
__global__ void k_detect(const unsigned char* m, unsigned* head, int nbytes) {
  int i = blockIdx.x * blockDim.x + threadIdx.x;
  int c0 = 0, c123 = 0;
  for (; i < nbytes; i += gridDim.x * blockDim.x) {
    unsigned char b = m[i];
    if (b) { if ((i & 3) == 0) c0++; else c123++; }
  }
  for (int o = 32; o; o >>= 1) { c0 += __shfl_xor(c0, o); c123 += __shfl_xor(c123, o); }
  if ((threadIdx.x & 63) == 0) {
    if (c0)   atomicAdd(&head[0], (unsigned)c0);
    if (c123) atomicAdd(&head[1], (unsigned)c123);
  }
}

__global__ void k_canon(const void* mraw, const unsigned* head, unsigned char* msk, int N) {
  unsigned c0 = head[0], c123 = head[1];
  int mode = (c123 == 0u) ? 1 : ((c0 == 0u) ? 2 : 0);
  int i = blockIdx.x * blockDim.x + threadIdx.x;
  for (; i < N; i += gridDim.x * blockDim.x) {
    unsigned char v;
    if (mode == 0)      v = (((const unsigned char*)mraw)[i] != 0);
    else if (mode == 1) v = (((const int*)mraw)[i] != 0);
    else                v = (((const float*)mraw)[i] != 0.0f);
    msk[i] = v;
  }
}

// rowmax[n] = max_f |x[n,f]|. One wave per node, lane = feature (F==64).
__global__ void k_rowmax(const float* x, float* rowmax, int N) {
  int w = (int)((blockIdx.x * blockDim.x + threadIdx.x) >> 6);
  int lane = threadIdx.x & 63;
  if (w >= N) return;
  float v = fabsf(x[(size_t)w * 64 + lane]);
  for (int o = 32; o; o >>= 1) v = fmaxf(v, __shfl_xor(v, o));
  if (lane == 0) rowmax[w] = v;
}

// One pass over edges: per-class amax of rowmax[src] (into spread slots) + dst histogram.
__global__ void k_edge(const int* src, const int* dst, const unsigned char* msk,
                       const float* rowmax, unsigned* cnt,
                       unsigned* slot_ehi, unsigned* slot_elo, int E) {
  int e = blockIdx.x * blockDim.x + threadIdx.x;
  float hi = 0.0f, lo = 0.0f;
  for (; e < E; e += gridDim.x * blockDim.x) {
    int s = src[e];
    float r = rowmax[s];
    if (msk[s]) hi = fmaxf(hi, r); else lo = fmaxf(lo, r);
    atomicAdd(&cnt[dst[e]], 1u);
  }
  for (int o = 32; o; o >>= 1) { hi = fmaxf(hi, __shfl_xor(hi, o)); lo = fmaxf(lo, __shfl_xor(lo, o)); }
  __shared__ float sh_hi[4], sh_lo[4];
  int wid = threadIdx.x >> 6, lane = threadIdx.x & 63;
  if (lane == 0) { sh_hi[wid] = hi; sh_lo[wid] = lo; }
  __syncthreads();
  if (threadIdx.x == 0) {
    float h = fmaxf(fmaxf(sh_hi[0], sh_hi[1]), fmaxf(sh_hi[2], sh_hi[3]));
    float l = fmaxf(fmaxf(sh_lo[0], sh_lo[1]), fmaxf(sh_lo[2], sh_lo[3]));
    atomicMax(&slot_ehi[blockIdx.x & 255], __float_as_uint(h));
    atomicMax(&slot_elo[blockIdx.x & 255], __float_as_uint(l));
  }
}

// Reduce 256-slot amax arrays -> scales. which=0: msg (hf[6,7]); which=1: out (hf[8,9]).
__global__ void k_scales(unsigned* head, const unsigned* shi, const unsigned* slo, int which) {
  __shared__ unsigned smh[256], sml[256];
  int t = threadIdx.x;
  smh[t] = shi[t]; sml[t] = slo[t];
  __syncthreads();
  for (int off = 128; off > 0; off >>= 1) {
    if (t < off) {
      smh[t] = smh[t] > smh[t + off] ? smh[t] : smh[t + off];
      sml[t] = sml[t] > sml[t + off] ? sml[t] : sml[t + off];
    }
    __syncthreads();
  }
  if (t == 0) {
    float* hf = (float*)head;
    float ah = __uint_as_float(smh[0]);
    float al = __uint_as_float(sml[0]);
    hf[6 + which * 2]     = __fdiv_rn(fmaxf(ah, 1e-8f), 127.0f);
    hf[6 + which * 2 + 1] = __fdiv_rn(fmaxf(al, 1e-8f), 7.0f);
  }
}

// Quantize x rows to int8 codes (value = scale * (float)code, bit-exact vs float path).
__global__ void k_quant8(const float* x, signed char* xq8, const unsigned char* msk,
                         const unsigned* head, int N) {
  int w = (int)((blockIdx.x * blockDim.x + threadIdx.x) >> 6);
  int lane = threadIdx.x & 63;
  if (w >= N) return;
  const float* hf = (const float*)head;
  bool m = msk[w] != 0;
  float sc = m ? hf[6] : hf[7];
  float qm = m ? 127.0f : 7.0f;
  float t = __fdiv_rn(x[(size_t)w * 64 + lane], sc);
  t = fminf(fmaxf(t, -qm), qm);
  t = rintf(t);
  xq8[(size_t)w * 64 + lane] = (signed char)t;
}

// Final fake-quant of output rows (in-place, float).
__global__ void k_quant_rows(const float* in, float* out, const unsigned char* msk,
                             const unsigned* head, int N) {
  int w = (int)((blockIdx.x * blockDim.x + threadIdx.x) >> 6);
  int lane = threadIdx.x & 63;
  if (w >= N) return;
  const float* hf = (const float*)head;
  bool m = msk[w] != 0;
  float sc = m ? hf[8] : hf[9];
  float qm = m ? 127.0f : 7.0f;
  float v = in[(size_t)w * 64 + lane];
  float t = __fdiv_rn(v, sc);
  t = fminf(fmaxf(t, -qm), qm);
  t = rintf(t);
  out[(size_t)w * 64 + lane] = __fmul_rn(sc, t);
}

// --- 3-kernel exclusive scan over cnt[N] -> start[N], chunk = 1024 ---
__global__ void k_scan_chunk_sum(const unsigned* cnt, unsigned* csum, int N) {
  int b = blockIdx.x, base = b * 1024;
  __shared__ unsigned sh[256];
  unsigned s = 0;
  for (int i = threadIdx.x; i < 1024; i += 256) {
    int idx = base + i;
    s += (idx < N) ? cnt[idx] : 0u;
  }
  sh[threadIdx.x] = s; __syncthreads();
  for (int off = 128; off > 0; off >>= 1) {
    if (threadIdx.x < (unsigned)off) sh[threadIdx.x] += sh[threadIdx.x + off];
    __syncthreads();
  }
  if (threadIdx.x == 0) csum[b] = sh[0];
}

__global__ void k_scan_carry(const unsigned* csum, unsigned* coff, int nchunks) {
  if (blockIdx.x == 0 && threadIdx.x == 0) {
    unsigned run = 0;
    for (int b = 0; b < nchunks; b++) { coff[b] = run; run += csum[b]; }
  }
}

__global__ void k_scan_within(const unsigned* cnt, const unsigned* coff, unsigned* start, int N) {
  int b = blockIdx.x, base = b * 1024, t = threadIdx.x;
  __shared__ unsigned sh[256];
  unsigned v[4]; unsigned s = 0;
  for (int j = 0; j < 4; j++) {
    int idx = base + t * 4 + j;
    v[j] = (idx < N) ? cnt[idx] : 0u;
    s += v[j];
  }
  sh[t] = s; __syncthreads();
  for (int off = 1; off < 256; off <<= 1) {
    unsigned a = sh[t];
    unsigned add = (t >= off) ? sh[t - off] : 0u;
    __syncthreads();
    sh[t] = a + add;
    __syncthreads();
  }
  unsigned excl = (t == 0) ? 0u : sh[t - 1];
  unsigned run = coff[b] + excl;
  for (int j = 0; j < 4; j++) {
    int idx = base + t * 4 + j;
    if (idx < N) start[idx] = run;
    run += v[j];
  }
}

// Placement: pos = postincrement of start[dst]; payload = (mask|src)<<32 | edge_id.
__global__ void k_place(const int* src, const int* dst, const unsigned char* msk,
                        unsigned* start, unsigned long long* opay, int E) {
  int e = blockIdx.x * blockDim.x + threadIdx.x;
  for (; e < E; e += gridDim.x * blockDim.x) {
    int s = src[e];
    unsigned pay = ((msk[s] != 0) ? 0x80000000u : 0u) | (unsigned)s;
    unsigned pos = atomicAdd(&start[dst[e]], 1u);
    opay[pos] = ((unsigned long long)pay << 32) | (unsigned)e;
  }
}

// Global insertion sort by edge id — only for (rare) nodes with degree > 64.
__global__ void k_sort_big(unsigned long long* opay, const unsigned* start,
                           const unsigned* cnt, int N) {
  int n = blockIdx.x * blockDim.x + threadIdx.x;
  for (; n < N; n += gridDim.x * blockDim.x) {
    unsigned d = cnt[n];
    if (d <= 64u) continue;
    unsigned s0 = start[n] - d;
    for (unsigned i = 1; i < d; i++) {
      unsigned long long key = opay[s0 + i];
      int j = (int)i - 1;
      while (j >= 0 && (unsigned)opay[s0 + j] > (unsigned)key) {
        opay[s0 + j + 1] = opay[s0 + j]; j--;
      }
      opay[s0 + (unsigned)(j + 1)] = key;
    }
  }
}

// One wave per node: in-register bitonic restore of edge order, then batched
// (16 loads in flight) sequential-order accumulation of int8 messages.
__global__ void k_aggr(const signed char* xq8, const float* x,
                       const unsigned long long* opay,
                       const unsigned* start, const unsigned* cnt,
                       const unsigned char* msk, const unsigned* head,
                       unsigned* slot_ohi, unsigned* slot_olo,
                       float* out, int N, int use_xq) {
  int w = (int)((blockIdx.x * blockDim.x + threadIdx.x) >> 6);
  int lane = threadIdx.x & 63;
  if (w >= N) return;
  unsigned d = cnt[w];
  unsigned s0 = start[w] - d;
  const float* hf = (const float*)head;
  float shi = hf[6], slo = hf[7];
  float acc = 0.0f;

  if (d <= 64u) {
    unsigned key = 0xFFFFFFFFu, pay = 0u;
    if ((unsigned)lane < d) {
      unsigned long long v = opay[s0 + (unsigned)lane];
      key = (unsigned)v;
      pay = (unsigned)(v >> 32);
    }
    // 64-lane bitonic sort ascending by key (unique edge ids), payload follows.
    #pragma unroll
    for (int size = 2; size <= 64; size <<= 1) {
      #pragma unroll
      for (int stride = size >> 1; stride > 0; stride >>= 1) {
        unsigned ok = __shfl_xor(key, stride);
        unsigned op = __shfl_xor(pay, stride);
        bool up = ((lane & size) == 0);
        bool keepMin = (((lane & stride) == 0) == up);
        bool sw = keepMin ? (ok < key) : (ok > key);
        if (sw) { key = ok; pay = op; }
      }
    }
    if (use_xq) {
      for (unsigned kb = 0; kb < d; kb += 16) {
        float vv[16];
        #pragma unroll
        for (int j = 0; j < 16; j++) {
          int sl = (int)kb + j; if (sl >= 64) sl = 0;
          unsigned p = __shfl(pay, sl);
          int sn = (int)(p & 0x7FFFFFFFu);
          float sc = (p & 0x80000000u) ? shi : slo;
          float val = __fmul_rn(sc, (float)xq8[(size_t)sn * 64 + lane]);
          vv[j] = (kb + (unsigned)j < d) ? val : 0.0f;
        }
        #pragma unroll
        for (int j = 0; j < 16; j++) acc = __fadd_rn(acc, vv[j]);
      }
    } else {
      for (unsigned kb = 0; kb < d; kb += 16) {
        float vv[16];
        #pragma unroll
        for (int j = 0; j < 16; j++) {
          int sl = (int)kb + j; if (sl >= 64) sl = 0;
          unsigned p = __shfl(pay, sl);
          int sn = (int)(p & 0x7FFFFFFFu);
          bool m = (p & 0x80000000u) != 0u;
          float sc = m ? shi : slo;
          float qm = m ? 127.0f : 7.0f;
          float t = __fdiv_rn(x[(size_t)sn * 64 + lane], sc);
          t = fminf(fmaxf(t, -qm), qm);
          t = rintf(t);
          float val = __fmul_rn(sc, t);
          vv[j] = (kb + (unsigned)j < d) ? val : 0.0f;
        }
        #pragma unroll
        for (int j = 0; j < 16; j++) acc = __fadd_rn(acc, vv[j]);
      }
    }
  } else {
    // rare big-degree path: globally sorted bucket, uniform sequential walk
    for (unsigned k = 0; k < d; k++) {
      unsigned long long v = opay[s0 + k];
      unsigned p = (unsigned)(v >> 32);
      int sn = (int)(p & 0x7FFFFFFFu);
      bool m = (p & 0x80000000u) != 0u;
      float sc = m ? shi : slo;
      float val;
      if (use_xq) {
        val = __fmul_rn(sc, (float)xq8[(size_t)sn * 64 + lane]);
      } else {
        float qm = m ? 127.0f : 7.0f;
        float t = __fdiv_rn(x[(size_t)sn * 64 + lane], sc);
        t = fminf(fmaxf(t, -qm), qm);
        t = rintf(t);
        val = __fmul_rn(sc, t);
      }
      acc = __fadd_rn(acc, val);
    }
  }

  out[(size_t)w * 64 + lane] = acc;

  float a = fabsf(acc);
  for (int o = 32; o; o >>= 1) a = fmaxf(a, __shfl_xor(a, o));
  if (lane == 0) {
    unsigned* sl = (msk[w] != 0) ? slot_ohi : slot_olo;
    atomicMax(&sl[blockIdx.x & 255], __float_as_uint(a));
  }
}

extern "C" void kernel_launch(void* const* d_in, const int* in_sizes, int n_in,
                              void* d_out, int out_size, void* d_ws, size_t ws_size,
                              hipStream_t stream) {
  const float* x = (const float*)d_in[0];
  const int* ei = (const int*)d_in[1];
  const void* mraw = d_in[2];
  int N = in_sizes[2];
  int E = in_sizes[1] / 2;
  const int* src = ei;
  const int* dst = ei + E;
  float* out = (float*)d_out;

  char* ws = (char*)d_ws;
  size_t o_sehi = 256, o_selo = 1280, o_sohi = 2304, o_solo = 3328;
  size_t o_csum = 4352, o_coff = 8448, o_msk = 12544;
  size_t o_rowmax = ((o_msk + (size_t)N + 255) / 256) * 256;
  size_t o_cnt = o_rowmax + (size_t)N * 4;
  size_t o_start = o_cnt + (size_t)N * 4;
  size_t o_opay = ((o_start + (size_t)N * 4 + 255) / 256) * 256;
  size_t o_xq8 = ((o_opay + (size_t)E * 8 + 255) / 256) * 256;
  size_t need_xq = o_xq8 + (size_t)N * 64;
  int use_xq = (ws_size >= need_xq) ? 1 : 0;

  unsigned* head = (unsigned*)ws;
  unsigned* slot_ehi = (unsigned*)(ws + o_sehi);
  unsigned* slot_elo = (unsigned*)(ws + o_selo);
  unsigned* slot_ohi = (unsigned*)(ws + o_sohi);
  unsigned* slot_olo = (unsigned*)(ws + o_solo);
  unsigned* csum = (unsigned*)(ws + o_csum);
  unsigned* coff = (unsigned*)(ws + o_coff);
  unsigned char* msk = (unsigned char*)(ws + o_msk);
  float* rowmax = (float*)(ws + o_rowmax);
  unsigned* cnt = (unsigned*)(ws + o_cnt);
  unsigned* start = (unsigned*)(ws + o_start);
  unsigned long long* opay = (unsigned long long*)(ws + o_opay);
  signed char* xq8 = (signed char*)(ws + o_xq8);

  int nchunks = (N + 1023) / 1024;
  int rowBlocks = (N + 3) / 4;  // 4 waves (nodes) per 256-thread block

  k_zero<<<4, 256, 0, stream>>>(head, 1088);              // head + 4 slot arrays
  k_zero<<<256, 256, 0, stream>>>(cnt, N);
  k_detect<<<256, 256, 0, stream>>>((const unsigned char*)mraw, head, N);
  k_canon<<<(N + 255) / 256, 256, 0, stream>>>(mraw, head, msk, N);
  k_rowmax<<<rowBlocks, 256, 0, stream>>>(x, rowmax, N);
  k_edge<<<1024, 256, 0, stream>>>(src, dst, msk, rowmax, cnt, slot_ehi, slot_elo, E);
  k_scales<<<1, 256, 0, stream>>>(head, slot_ehi, slot_elo, 0);
  if (use_xq) k_quant8<<<rowBlocks, 256, 0, stream>>>(x, xq8, msk, head, N);
  k_scan_chunk_sum<<<nchunks, 256, 0, stream>>>(cnt, csum, N);
  k_scan_carry<<<1, 64, 0, stream>>>(csum, coff, nchunks);
  k_scan_within<<<nchunks, 256, 0, stream>>>(cnt, coff, start, N);
  k_place<<<1024, 256, 0, stream>>>(src, dst, msk, start, opay, E);
  k_sort_big<<<(N + 255) / 256, 256, 0, stream>>>(opay, start, cnt, N);
  k_aggr<<<rowBlocks, 256, 0, stream>>>(xq8, x, opay, start, cnt, msk, head,
                                        slot_ohi, slot_olo, out, N, use_xq);
  k_scales<<<1, 256, 0, stream>>>(head, slot_ohi, slot_olo, 1);
  k_quant_rows<<<rowBlocks, 256, 0, stream>>>(out, out, msk, head, N);
}